// Round 2
// 535.762 us; speedup vs baseline: 1.7787x; 1.7787x over previous
//
#include <hip/hip_runtime.h>

// EvenOddConvLayer MFMA v4.1. N=50000, M=20, EVEN=ODD=64, EDGE=32, CAT=224.
// v3 structure with the LDS diet for 3 blocks/CU (was 2):
//  - even_i is per-GROUP: dropped from cat (stride 232->168); its W_em1/W_ogh
//    K=0..63 contribution + the whole W_pei product come from a 6-MFMA "tiny
//    GEMM" on 4 rows, added as per-group bias in epilogue 1 (pg, bf16).
//  - oj time-shares the oh buffer: staged there, read in epilogue 1 by the
//    exact thread that then overwrites the slot with oh (same (row,col) owner).
//  - nbr_fea staging full-wave (2 rows / iter, 256B coalesced).
// LDS 72704 -> 52992 => 3 blocks/CU (52992->53248 granule, x3 = 159744 <= 160K).
// GEMM1 shrinks 7->5 ks steps; MFMAs/wave 140 -> 116.
// v4.1: fix launcher arg unpack (W_og/b_og) — v4 never compiled.

#define NN    50000
#define GN    4
#define MT    5
#define CSTR  168      // cat row stride (shorts): [ej 0 | nbr 64 | cross 96]
#define ESTR  72       // eh / oh row stride (shorts), 144B = 16B-aligned rows
#define IOSTR 136      // io row stride (shorts): [ie 0 | ieo 64]
#define RSTR  68       // red_e / red_o row stride (floats)

#define LDS_A   0      // cat(26880) -> io(21760) -> red_e(21760)
#define LDS_EH  26880  // eh (11520); red_o(21760) overlays eh+oh
#define LDS_OH  38400  // oh (11520); oj staged here until epilogue 1
#define LDS_OI  49920  // oi 4x64 f32 (1024)
#define LDS_EI  50944  // ei 4x64 bf16 (512)
#define LDS_PG  51456  // per-group partials 3x4x64 bf16 (1536), bias folded in
#define LDS_SZ  52992

typedef __attribute__((ext_vector_type(8))) short  short8;
typedef __attribute__((ext_vector_type(4))) float  floatx4;

__device__ unsigned char g_wbuf[114688];

#define OFF_EM1 0
#define OFF_OGH 28672
#define OFF_EG  57344
#define OFF_EM2 65536
#define OFF_OG  73728
#define OFF_PEJ 81920
#define OFF_PEI 90112
#define OFF_OM1 98304

__device__ __forceinline__ unsigned short f2b(float x) {        // RNE fp32->bf16
    unsigned u = __float_as_uint(x);
    return (unsigned short)((u + 0x7fffu + ((u >> 16) & 1u)) >> 16);
}
__device__ __forceinline__ float b2f(unsigned short s) {
    return __uint_as_float(((unsigned)s) << 16);
}
__device__ __forceinline__ float spf(float x) {                 // softplus, fast
    return fmaxf(x, 0.f) + __logf(1.f + __expf(-fabsf(x)));
}
__device__ __forceinline__ float sgf(float x) {                 // sigmoid, fast
    return __builtin_amdgcn_rcpf(1.f + __expf(-x));
}
__device__ __forceinline__ float thf(float x) {                 // tanh, fast
    float e = __expf(-2.f * fabsf(x));
    float t = (1.f - e) * __builtin_amdgcn_rcpf(1.f + e);
    return __builtin_copysignf(t, x);
}
__device__ __forceinline__ floatx4 mfma16(short8 a, short8 b, floatx4 c) {
    return __builtin_amdgcn_mfma_f32_16x16x32_bf16(a, b, c, 0, 0, 0);
}
__device__ __forceinline__ short8 wfrag(int base, int s, int t, int l) {
    return *(const short8*)(g_wbuf + base + ((size_t)((s * 4 + t) * 64 + l)) * 16);
}

// ---------------- weight prepack (identical to round 3, verified) -----------
__global__ __launch_bounds__(256) void prepack(
    const float* __restrict__ W_em1, const float* __restrict__ W_ogh,
    const float* __restrict__ W_eg,  const float* __restrict__ W_em2,
    const float* __restrict__ W_og,  const float* __restrict__ W_pej,
    const float* __restrict__ W_pei, const float* __restrict__ W_om1)
{
    int tid = blockIdx.x * 256 + threadIdx.x;
    int gid = tid >> 6, l = tid & 63;
    const float* W; int base, gl;
    if      (gid < 28) { W = W_em1; base = OFF_EM1; gl = gid;      }
    else if (gid < 56) { W = W_ogh; base = OFF_OGH; gl = gid - 28; }
    else if (gid < 64) { W = W_eg;  base = OFF_EG;  gl = gid - 56; }
    else if (gid < 72) { W = W_em2; base = OFF_EM2; gl = gid - 64; }
    else if (gid < 80) { W = W_og;  base = OFF_OG;  gl = gid - 72; }
    else if (gid < 88) { W = W_pej; base = OFF_PEJ; gl = gid - 80; }
    else if (gid < 96) { W = W_pei; base = OFF_PEI; gl = gid - 88; }
    else               { W = W_om1; base = OFF_OM1; gl = gid - 96; }
    int s = gl >> 2, t = gl & 3;
    int k0 = s * 32 + (l >> 4) * 8;
    int n  = t * 16 + (l & 15);
    short8 pk;
    #pragma unroll
    for (int j = 0; j < 8; ++j) pk[j] = (short)f2b(W[(size_t)(k0 + j) * 64 + n]);
    *(short8*)(g_wbuf + base + ((size_t)((s * 4 + t) * 64 + l)) * 16) = pk;
}

// ---------------- main kernel ------------------------------------------------
__global__ __launch_bounds__(256, 3) void eoconv_mfma(
    const float* __restrict__ even_node, const float* __restrict__ odd_node,
    const float* __restrict__ nbr_fea,   const int* __restrict__ nbr_idx,
    const float* __restrict__ b_em1, const float* __restrict__ b_eg,
    const float* __restrict__ b_em2, const float* __restrict__ b_pej,
    const float* __restrict__ b_pei, const float* __restrict__ b_ogh,
    const float* __restrict__ b_og,  float* __restrict__ out)
{
    extern __shared__ char smem[];
    short* sh_cat = (short*)(smem + LDS_A);
    short* sh_io  = (short*)(smem + LDS_A);
    float* red_e  = (float*)(smem + LDS_A);
    short* sh_eh  = (short*)(smem + LDS_EH);
    float* red_o  = (float*)(smem + LDS_EH);
    short* sh_oh  = (short*)(smem + LDS_OH);
    float* sh_oi  = (float*)(smem + LDS_OI);
    short* sh_ei  = (short*)(smem + LDS_EI);
    short* sh_pg  = (short*)(smem + LDS_PG);

    const int w  = threadIdx.x >> 6;
    const int l  = threadIdx.x & 63;
    const int n0 = blockIdx.x * GN;

    // ---- stage node w's 20 pair rows
    const float eif = even_node[(long)(n0 + w) * 64 + l];
    const float oif = odd_node [(long)(n0 + w) * 64 + l];
    sh_oi[w * 64 + l] = oif;
    sh_ei[w * 64 + l] = (short)f2b(eif);
    #pragma unroll 2
    for (int i2 = 0; i2 < 20; i2 += 2) {            // nbr: full wave, 2 rows/iter
        const int  ii = i2 + (l >> 5);
        const int  cc = l & 31;
        const long p  = (long)(n0 + w) * 20 + ii;
        sh_cat[(w * 20 + ii) * CSTR + 64 + cc] = (short)f2b(nbr_fea[p * 32 + cc]);
    }
    #pragma unroll 4
    for (int i = 0; i < 20; ++i) {
        const int  r = w * 20 + i;
        const long p = (long)(n0 + w) * 20 + i;
        const int  j = nbr_idx[p];
        const float ejf = even_node[(long)j * 64 + l];
        const float ojf = odd_node [(long)j * 64 + l];
        sh_cat[r * CSTR + l]      = (short)f2b(ejf);
        sh_cat[r * CSTR + 96 + l] = (short)f2b(oif * ojf);
        sh_oh [r * ESTR + l]      = (short)f2b(ojf);       // oj parked in oh slot
    }
    __syncthreads();

    const int col = w * 16 + (l & 15);
    const int q8  = (l >> 4) * 8;
    const int q4  = (l >> 4) * 4;
    const float be1 = b_em1[col], bgh = b_ogh[col], bpi = b_pei[col], bpj = b_pej[col];
    const floatx4 z4 = {0.f, 0.f, 0.f, 0.f};

    // ---- tiny GEMM: per-group ei @ {W_em1[0:64], W_ogh[0:64], W_pei} (rows 0..3)
    {
        floatx4 Tm = z4, Tg = z4, Tp = z4;
        #pragma unroll
        for (int ks = 0; ks < 2; ++ks) {
            short8 Ae = *(const short8*)&sh_ei[((l & 3)) * 64 + ks * 32 + q8];
            Tm = mfma16(Ae, wfrag(OFF_EM1, ks, w, l), Tm);
            Tg = mfma16(Ae, wfrag(OFF_OGH, ks, w, l), Tg);
            Tp = mfma16(Ae, wfrag(OFF_PEI, ks, w, l), Tp);
        }
        if (l < 16) {                                // rows 0..3 = groups, bias folded
            #pragma unroll
            for (int rg = 0; rg < 4; ++rg) {
                sh_pg[      rg * 64 + col] = (short)f2b(Tm[rg] + be1);
                sh_pg[256 + rg * 64 + col] = (short)f2b(Tg[rg] + bgh);
                sh_pg[512 + rg * 64 + col] = (short)f2b(Tp[rg] + bpi);
            }
        }
    }

    // ---- GEMM1: [ej|nbr|cross] @ {W_em1[64:],W_ogh[64:]}; ej @ W_pej
    floatx4 C1[MT], Cg[MT], Cpj[MT];
    #pragma unroll
    for (int t = 0; t < MT; ++t) { C1[t] = z4; Cg[t] = z4; Cpj[t] = z4; }
    #pragma unroll
    for (int ks = 0; ks < 5; ++ks) {
        short8 B1 = wfrag(OFF_EM1, ks + 2, w, l);
        short8 Bg = wfrag(OFF_OGH, ks + 2, w, l);
        short8 Bx = B1;
        if (ks < 2) Bx = wfrag(OFF_PEJ, ks, w, l);
        const int ko = ks * 32 + q8;
        #pragma unroll
        for (int t = 0; t < MT; ++t) {
            short8 A = *(const short8*)&sh_cat[(t * 16 + (l & 15)) * CSTR + ko];
            C1[t] = mfma16(A, B1, C1[t]);
            Cg[t] = mfma16(A, Bg, Cg[t]);
            if (ks < 2) Cpj[t] = mfma16(A, Bx, Cpj[t]);
        }
    }

    // ---- epilogue 1: read oj, then overwrite slot with oh; eh to LDS;
    //      ie/ieo packed in regs. Same thread owns the oj read AND oh write.
    unsigned pk[MT][4];
    #pragma unroll
    for (int t = 0; t < MT; ++t) {
        const int r0 = t * 16 + q4;
        const int g  = r0 / 20;                      // 4-aligned spans never straddle 20
        const float em1g = b2f((unsigned short)sh_pg[      g * 64 + col]);
        const float oghg = b2f((unsigned short)sh_pg[256 + g * 64 + col]);
        const float peig = b2f((unsigned short)sh_pg[512 + g * 64 + col]);
        const float oi   = sh_oi[g * 64 + col];
        float ojv[4];
        #pragma unroll
        for (int rg = 0; rg < 4; ++rg)               // read all oj first (WAR safety)
            ojv[rg] = b2f((unsigned short)sh_oh[(r0 + rg) * ESTR + col]);
        #pragma unroll
        for (int rg = 0; rg < 4; ++rg) {
            const int row = r0 + rg;
            const float pj = Cpj[t][rg] + bpj;
            pk[t][rg] = (unsigned)f2b(oi * pj) | ((unsigned)f2b(peig * ojv[rg]) << 16);
            sh_eh[row * ESTR + col] = (short)f2b(spf(C1[t][rg] + em1g));
            sh_oh[row * ESTR + col] = (short)f2b(spf(Cg[t][rg] + oghg));
        }
    }
    __syncthreads();                               // all cat reads complete

    #pragma unroll
    for (int t = 0; t < MT; ++t) {
        #pragma unroll
        for (int rg = 0; rg < 4; ++rg) {
            const int row = t * 16 + q4 + rg;
            sh_io[row * IOSTR + col]      = (short)(pk[t][rg] & 0xffffu);
            sh_io[row * IOSTR + 64 + col] = (short)(pk[t][rg] >> 16);
        }
    }

    // ---- GEMM2: eh@{W_eg,W_em2}, oh@W_og (K=64)
    floatx4 Gg[MT], Gm[MT], Go[MT];
    #pragma unroll
    for (int t = 0; t < MT; ++t) { Gg[t] = z4; Gm[t] = z4; Go[t] = z4; }
    #pragma unroll
    for (int ks = 0; ks < 2; ++ks) {
        short8 Beg = wfrag(OFF_EG,  ks, w, l);
        short8 Bm2 = wfrag(OFF_EM2, ks, w, l);
        short8 Bog = wfrag(OFF_OG,  ks, w, l);
        const int ko = ks * 32 + q8;
        #pragma unroll
        for (int t = 0; t < MT; ++t) {
            short8 Ae = *(const short8*)&sh_eh[(t * 16 + (l & 15)) * ESTR + ko];
            short8 Ao = *(const short8*)&sh_oh[(t * 16 + (l & 15)) * ESTR + ko];
            Gg[t] = mfma16(Ae, Beg, Gg[t]);
            Gm[t] = mfma16(Ae, Bm2, Gm[t]);
            Go[t] = mfma16(Ao, Bog, Go[t]);
        }
    }
    __syncthreads();                               // io visible

    // ---- GEMM3: [ie|ieo] @ W_om1 (K=128)
    floatx4 Gt[MT];
    #pragma unroll
    for (int t = 0; t < MT; ++t) Gt[t] = z4;
    #pragma unroll
    for (int ks = 0; ks < 4; ++ks) {
        short8 Bo = wfrag(OFF_OM1, ks, w, l);
        const int ko = ks * 32 + q8;
        #pragma unroll
        for (int t = 0; t < MT; ++t) {
            short8 Ai = *(const short8*)&sh_io[(t * 16 + (l & 15)) * IOSTR + ko];
            Gt[t] = mfma16(Ai, Bo, Gt[t]);
        }
    }
    __syncthreads();                               // io/eh/oh reads done (red overlays)

    // ---- epilogue 2: gates, per-pair contributions
    {
        const float beg = b_eg[col], bm2 = b_em2[col], bog = b_og[col];
        #pragma unroll
        for (int t = 0; t < MT; ++t) {
            #pragma unroll
            for (int rg = 0; rg < 4; ++rg) {
                const int row = t * 16 + q4 + rg;
                red_e[row * RSTR + col] = sgf(Gg[t][rg] + beg) * spf(Gm[t][rg] + bm2);
                red_o[row * RSTR + col] = sgf(Go[t][rg] + bog) * thf(Gt[t][rg]);
            }
        }
    }
    __syncthreads();

    // ---- reduce 20 pairs (wave w -> node w), residual, store
    {
        float se = 0.f, so = 0.f;
        #pragma unroll 4
        for (int i = 0; i < 20; ++i) {
            se += red_e[(w * 20 + i) * RSTR + l];
            so += red_o[(w * 20 + i) * RSTR + l];
        }
        const long nb = (long)(n0 + w) * 64 + l;
        out[nb]                 = eif + se;
        out[(long)NN * 64 + nb] = oif + so;
    }
}

extern "C" void kernel_launch(void* const* d_in, const int* in_sizes, int n_in,
                              void* d_out, int out_size, void* d_ws, size_t ws_size,
                              hipStream_t stream) {
    const float* even_node = (const float*)d_in[0];
    const float* odd_node  = (const float*)d_in[1];
    const float* nbr_fea   = (const float*)d_in[2];
    const int*   nbr_idx   = (const int*)d_in[3];
    const float* W_em1 = (const float*)d_in[4];
    const float* b_em1 = (const float*)d_in[5];
    const float* W_eg  = (const float*)d_in[6];
    const float* b_eg  = (const float*)d_in[7];
    const float* W_em2 = (const float*)d_in[8];
    const float* b_em2 = (const float*)d_in[9];
    const float* W_pej = (const float*)d_in[10];
    const float* b_pej = (const float*)d_in[11];
    const float* W_pei = (const float*)d_in[12];
    const float* b_pei = (const float*)d_in[13];
    const float* W_om1 = (const float*)d_in[14];
    const float* W_ogh = (const float*)d_in[15];
    const float* b_ogh = (const float*)d_in[16];
    const float* W_og  = (const float*)d_in[17];
    const float* b_og  = (const float*)d_in[18];

    static int s_attr_done = 0;                     // host-side config, idempotent
    if (!s_attr_done) {
        (void)hipFuncSetAttribute((const void*)eoconv_mfma,
                                  hipFuncAttributeMaxDynamicSharedMemorySize, LDS_SZ);
        s_attr_done = 1;
    }

    prepack<<<dim3(28), dim3(256), 0, stream>>>(W_em1, W_ogh, W_eg, W_em2,
                                                W_og, W_pej, W_pei, W_om1);
    eoconv_mfma<<<dim3(NN / GN), dim3(256), LDS_SZ, stream>>>(
        even_node, odd_node, nbr_fea, nbr_idx,
        b_em1, b_eg, b_em2, b_pej, b_pei, b_ogh, b_og,
        (float*)d_out);
}

// Round 3
// 516.535 us; speedup vs baseline: 1.8449x; 1.0372x over previous
//
#include <hip/hip_runtime.h>

// EvenOddConvLayer MFMA v5. N=50000, M=20, EVEN=ODD=64, EDGE=32, CAT=224.
// v4.1 (380us kernel, VALU-bound 64%, 3 blk/CU) -> attack VALU + occupancy:
//  - 4 blocks/CU: LDS 52992 -> 39680.  region1(20480) = [ej|cross] (stride 128,
//    XOR-swz) -> eh|oh (stride 64, swz) after GEMM1 -> io (stride 128, swz)
//    after GEMM2. nbr in its own buffer (stride 40 shorts: conflict-free).
//    red_e/red_o LDS deleted entirely (register reduction).
//  - pair-row permutation: pair(g,i) -> row 4*i+g, so group == rg statically:
//    no /20 division, per-group epi1 constants hoisted, and epilogue-2
//    accumulates into acc_e[rg]/acc_o[rg] registers + quad butterfly shfl.
//    Residuals re-read from global (L2-hot) at the end.
//  - vectorized staging: float4 ej/oj gathers (4 rows/iter), float2 nbr,
//    j-prefetch; v_cvt_pk_bf16_f32 (1 op) replaces 4-op software f2b.
//  - barriers 6 -> 5; __launch_bounds__(256,4).

#define NN    50000
#define GN    4
#define MT    5
#define ECSTR 128      // ej_cross row stride (shorts): [ej 0 | cross 64], swz
#define NSTR  40       // nbr row stride (shorts), no swz needed
#define ESTR  64       // eh / oh / oj row stride (shorts), swz
#define IOSTR 128      // io row stride (shorts): [ie 0 | ieo 64], swz

#define LDS_EJC 0      // ej_cross(20480) -> eh@0 oh@10240 -> io(20480)
#define LDS_NBR 20480  // nbr 80x40sh (6400)
#define LDS_OJ  26880  // oj 80x64sh (10240), swz
#define LDS_OIB 37120  // oi bf16 4x64 (512)
#define LDS_EIB 37632  // ei bf16 4x64 (512)
#define LDS_PG  38144  // per-group partials 3x4x64 bf16 (1536), bias folded
#define LDS_SZ  39680

typedef __attribute__((ext_vector_type(8))) short  short8;
typedef __attribute__((ext_vector_type(4))) float  floatx4;

__device__ unsigned char g_wbuf[114688];

#define OFF_EM1 0
#define OFF_OGH 28672
#define OFF_EG  57344
#define OFF_EM2 65536
#define OFF_OG  73728
#define OFF_PEJ 81920
#define OFF_PEI 90112
#define OFF_OM1 98304

__device__ __forceinline__ unsigned cvtpk(float lo, float hi) {   // 2x fp32->bf16 RNE
    unsigned r;
    asm("v_cvt_pk_bf16_f32 %0, %1, %2" : "=v"(r) : "v"(lo), "v"(hi));
    return r;
}
__device__ __forceinline__ unsigned short f2b(float x) {          // RNE fp32->bf16
    unsigned u = __float_as_uint(x);
    return (unsigned short)((u + 0x7fffu + ((u >> 16) & 1u)) >> 16);
}
__device__ __forceinline__ float b2f(unsigned short s) {
    return __uint_as_float(((unsigned)s) << 16);
}
__device__ __forceinline__ float spf(float x) {                   // softplus, fast
    return fmaxf(x, 0.f) + __logf(1.f + __expf(-fabsf(x)));
}
__device__ __forceinline__ float sgf(float x) {                   // sigmoid, fast
    return __builtin_amdgcn_rcpf(1.f + __expf(-x));
}
__device__ __forceinline__ float thf(float x) {                   // tanh, fast
    float e = __expf(-2.f * fabsf(x));
    float t = (1.f - e) * __builtin_amdgcn_rcpf(1.f + e);
    return __builtin_copysignf(t, x);
}
__device__ __forceinline__ floatx4 mfma16(short8 a, short8 b, floatx4 c) {
    return __builtin_amdgcn_mfma_f32_16x16x32_bf16(a, b, c, 0, 0, 0);
}
__device__ __forceinline__ short8 wfrag(int base, int s, int t, int l) {
    return *(const short8*)(g_wbuf + base + ((size_t)((s * 4 + t) * 64 + l)) * 16);
}

// ---------------- weight prepack (identical, verified) ----------------------
__global__ __launch_bounds__(256) void prepack(
    const float* __restrict__ W_em1, const float* __restrict__ W_ogh,
    const float* __restrict__ W_eg,  const float* __restrict__ W_em2,
    const float* __restrict__ W_og,  const float* __restrict__ W_pej,
    const float* __restrict__ W_pei, const float* __restrict__ W_om1)
{
    int tid = blockIdx.x * 256 + threadIdx.x;
    int gid = tid >> 6, l = tid & 63;
    const float* W; int base, gl;
    if      (gid < 28) { W = W_em1; base = OFF_EM1; gl = gid;      }
    else if (gid < 56) { W = W_ogh; base = OFF_OGH; gl = gid - 28; }
    else if (gid < 64) { W = W_eg;  base = OFF_EG;  gl = gid - 56; }
    else if (gid < 72) { W = W_em2; base = OFF_EM2; gl = gid - 64; }
    else if (gid < 80) { W = W_og;  base = OFF_OG;  gl = gid - 72; }
    else if (gid < 88) { W = W_pej; base = OFF_PEJ; gl = gid - 80; }
    else if (gid < 96) { W = W_pei; base = OFF_PEI; gl = gid - 88; }
    else               { W = W_om1; base = OFF_OM1; gl = gid - 96; }
    int s = gl >> 2, t = gl & 3;
    int k0 = s * 32 + (l >> 4) * 8;
    int n  = t * 16 + (l & 15);
    short8 pk;
    #pragma unroll
    for (int j = 0; j < 8; ++j) pk[j] = (short)f2b(W[(size_t)(k0 + j) * 64 + n]);
    *(short8*)(g_wbuf + base + ((size_t)((s * 4 + t) * 64 + l)) * 16) = pk;
}

// ---------------- main kernel ------------------------------------------------
__global__ __launch_bounds__(256, 4) void eoconv_mfma(
    const float* __restrict__ even_node, const float* __restrict__ odd_node,
    const float* __restrict__ nbr_fea,   const int* __restrict__ nbr_idx,
    const float* __restrict__ b_em1, const float* __restrict__ b_eg,
    const float* __restrict__ b_em2, const float* __restrict__ b_pej,
    const float* __restrict__ b_pei, const float* __restrict__ b_ogh,
    const float* __restrict__ b_og,  float* __restrict__ out)
{
    extern __shared__ char smem[];
    short* sh_ejc = (short*)(smem + LDS_EJC);
    short* sh_eh  = (short*)(smem + LDS_EJC);          // overlay after GEMM1
    short* sh_oh  = (short*)(smem + LDS_EJC + 10240);  // overlay after GEMM1
    short* sh_io  = (short*)(smem + LDS_EJC);          // overlay after GEMM2
    short* sh_nbr = (short*)(smem + LDS_NBR);
    short* sh_oj  = (short*)(smem + LDS_OJ);
    short* sh_oib = (short*)(smem + LDS_OIB);
    short* sh_eib = (short*)(smem + LDS_EIB);
    short* sh_pg  = (short*)(smem + LDS_PG);

    const int w  = threadIdx.x >> 6;
    const int l  = threadIdx.x & 63;
    const int n0 = blockIdx.x * GN;

    // ---- stage: wave w owns group w (rows 4*i+w). float4 gathers, 4 rows/iter.
    const float eif = even_node[(long)(n0 + w) * 64 + l];
    const float oif = odd_node [(long)(n0 + w) * 64 + l];
    sh_oib[w * 64 + l] = (short)cvtpk(oif, oif);
    sh_eib[w * 64 + l] = (short)cvtpk(eif, eif);

    const long jb = (long)(n0 + w) * 20;
    int jv[5];
    #pragma unroll
    for (int c = 0; c < 5; ++c) jv[c] = nbr_idx[jb + c * 4 + (l >> 4)];

    // oi at this lane's 4 staging cols (fixed across iters) via shuffle
    const int c0 = (l & 15) * 4;
    float oi0 = __shfl(oif, c0), oi1 = __shfl(oif, c0 + 1);
    float oi2 = __shfl(oif, c0 + 2), oi3 = __shfl(oif, c0 + 3);

    #pragma unroll
    for (int c = 0; c < 5; ++c) {
        const int  iw  = c * 4 + (l >> 4);        // pair index 0..19
        const int  row = iw * 4 + w;              // permuted row
        const int  j   = jv[c];
        const int  sz  = (row & 7) << 3;
        const float4 ej4 = *(const float4*)&even_node[(long)j * 64 + c0];
        const float4 oj4 = *(const float4*)&odd_node [(long)j * 64 + c0];
        // ej -> ejc[row][c0..c0+3]
        *(int2*)&sh_ejc[(row * ECSTR + c0) ^ sz] =
            make_int2((int)cvtpk(ej4.x, ej4.y), (int)cvtpk(ej4.z, ej4.w));
        // cross -> ejc[row][64+c0..]
        *(int2*)&sh_ejc[(row * ECSTR + 64 + c0) ^ sz] =
            make_int2((int)cvtpk(oi0 * oj4.x, oi1 * oj4.y),
                      (int)cvtpk(oi2 * oj4.z, oi3 * oj4.w));
        // oj -> oj[row][c0..]
        *(int2*)&sh_oj[(row * ESTR + c0) ^ sz] =
            make_int2((int)cvtpk(oj4.x, oj4.y), (int)cvtpk(oj4.z, oj4.w));
        // nbr: float2, 16 lanes x 2 cols
        const float2 nb2 = *(const float2*)&nbr_fea[(jb + iw) * 32 + (l & 15) * 2];
        *(int*)&sh_nbr[row * NSTR + (l & 15) * 2] = (int)cvtpk(nb2.x, nb2.y);
    }
    __syncthreads();                               // s1: staging visible

    const int col = w * 16 + (l & 15);
    const int q8  = (l >> 4) * 8;
    const int q4  = (l >> 4) * 4;
    const int lsz = (l & 7) << 3;                  // swz for all A-read rows
    const float be1 = b_em1[col], bgh = b_ogh[col], bpi = b_pei[col], bpj = b_pej[col];
    const floatx4 z4 = {0.f, 0.f, 0.f, 0.f};

    // ---- tiny GEMM: per-group ei @ {W_em1[0:64], W_ogh[0:64], W_pei} (rows 0..3)
    {
        floatx4 Tm = z4, Tg = z4, Tp = z4;
        #pragma unroll
        for (int ks = 0; ks < 2; ++ks) {
            short8 Ae = *(const short8*)&sh_eib[(l & 3) * 64 + ks * 32 + q8];
            Tm = mfma16(Ae, wfrag(OFF_EM1, ks, w, l), Tm);
            Tg = mfma16(Ae, wfrag(OFF_OGH, ks, w, l), Tg);
            Tp = mfma16(Ae, wfrag(OFF_PEI, ks, w, l), Tp);
        }
        if (l < 16) {                              // rows 0..3 = groups, bias folded
            #pragma unroll
            for (int rg = 0; rg < 4; ++rg) {
                sh_pg[      rg * 64 + col] = (short)cvtpk(Tm[rg] + be1, 0.f);
                sh_pg[256 + rg * 64 + col] = (short)cvtpk(Tg[rg] + bgh, 0.f);
                sh_pg[512 + rg * 64 + col] = (short)cvtpk(Tp[rg] + bpi, 0.f);
            }
        }
    }

    // ---- GEMM1: [ej|nbr|cross] @ {W_em1[64:],W_ogh[64:]}; ej @ W_pej
    floatx4 C1[MT], Cg[MT], Cpj[MT];
    #pragma unroll
    for (int t = 0; t < MT; ++t) { C1[t] = z4; Cg[t] = z4; Cpj[t] = z4; }
    #pragma unroll
    for (int ks = 0; ks < 5; ++ks) {
        short8 B1 = wfrag(OFF_EM1, ks + 2, w, l);
        short8 Bg = wfrag(OFF_OGH, ks + 2, w, l);
        short8 Bx = B1;
        if (ks < 2) Bx = wfrag(OFF_PEJ, ks, w, l);
        const int ko = ks * 32 + q8;
        #pragma unroll
        for (int t = 0; t < MT; ++t) {
            const int row = t * 16 + (l & 15);
            short8 A;
            if (ks == 2) A = *(const short8*)&sh_nbr[row * NSTR + q8];
            else         A = *(const short8*)&sh_ejc[(row * ECSTR +
                                (ks < 2 ? ko : ko - 32)) ^ lsz];
            C1[t] = mfma16(A, B1, C1[t]);
            Cg[t] = mfma16(A, Bg, Cg[t]);
            if (ks < 2) Cpj[t] = mfma16(A, Bx, Cpj[t]);
        }
    }
    __syncthreads();                               // s2: ej_cross dead -> eh/oh land

    // ---- epilogue 1: eh/oh into old cat region; ie/ieo packed in regs.
    unsigned pk[MT][4];
    {
        float em1g[4], oghg[4], peig[4], oiv[4];
        #pragma unroll
        for (int rg = 0; rg < 4; ++rg) {           // group == rg (row = 4i+g perm)
            em1g[rg] = b2f((unsigned short)sh_pg[      rg * 64 + col]);
            oghg[rg] = b2f((unsigned short)sh_pg[256 + rg * 64 + col]);
            peig[rg] = b2f((unsigned short)sh_pg[512 + rg * 64 + col]);
            oiv [rg] = b2f((unsigned short)sh_oib[rg * 64 + col]);
        }
        #pragma unroll
        for (int t = 0; t < MT; ++t) {
            #pragma unroll
            for (int rg = 0; rg < 4; ++rg) {
                const int row = t * 16 + q4 + rg;
                const int sz  = (row & 7) << 3;
                const float ojr = b2f((unsigned short)sh_oj[(row * ESTR + col) ^ sz]);
                const float pj  = Cpj[t][rg] + bpj;
                pk[t][rg] = cvtpk(oiv[rg] * pj, peig[rg] * ojr);
                const float ehv = spf(C1[t][rg] + em1g[rg]);
                const float ohv = spf(Cg[t][rg] + oghg[rg]);
                sh_eh[(row * ESTR + col) ^ sz] = (short)cvtpk(ehv, 0.f);
                sh_oh[(row * ESTR + col) ^ sz] = (short)cvtpk(ohv, 0.f);
            }
        }
    }
    __syncthreads();                               // s3: eh/oh visible

    // ---- GEMM2: eh@{W_eg,W_em2}, oh@W_og (K=64)
    floatx4 Gg[MT], Gm[MT], Go[MT];
    #pragma unroll
    for (int t = 0; t < MT; ++t) { Gg[t] = z4; Gm[t] = z4; Go[t] = z4; }
    #pragma unroll
    for (int ks = 0; ks < 2; ++ks) {
        short8 Beg = wfrag(OFF_EG,  ks, w, l);
        short8 Bm2 = wfrag(OFF_EM2, ks, w, l);
        short8 Bog = wfrag(OFF_OG,  ks, w, l);
        const int ko = ks * 32 + q8;
        #pragma unroll
        for (int t = 0; t < MT; ++t) {
            const int row = t * 16 + (l & 15);
            short8 Ae = *(const short8*)&sh_eh[(row * ESTR + ko) ^ lsz];
            short8 Ao = *(const short8*)&sh_oh[(row * ESTR + ko) ^ lsz];
            Gg[t] = mfma16(Ae, Beg, Gg[t]);
            Gm[t] = mfma16(Ae, Bm2, Gm[t]);
            Go[t] = mfma16(Ao, Bog, Go[t]);
        }
    }

    // ---- epilogue 2a (even): accumulate into registers, frees Gg/Gm
    float acc_e[4] = {0.f, 0.f, 0.f, 0.f};
    {
        const float beg = b_eg[col], bm2 = b_em2[col];
        #pragma unroll
        for (int t = 0; t < MT; ++t)
            #pragma unroll
            for (int rg = 0; rg < 4; ++rg)
                acc_e[rg] += sgf(Gg[t][rg] + beg) * spf(Gm[t][rg] + bm2);
    }
    __syncthreads();                               // s4: eh/oh dead -> io lands

    #pragma unroll
    for (int t = 0; t < MT; ++t) {
        #pragma unroll
        for (int rg = 0; rg < 4; ++rg) {
            const int row = t * 16 + q4 + rg;
            const int sz  = (row & 7) << 3;
            sh_io[(row * IOSTR + col) ^ sz]      = (short)pk[t][rg];
            sh_io[(row * IOSTR + 64 + col) ^ sz] = (short)(pk[t][rg] >> 16);
        }
    }
    __syncthreads();                               // s5: io visible

    // ---- GEMM3: [ie|ieo] @ W_om1 (K=128)
    floatx4 Gt[MT];
    #pragma unroll
    for (int t = 0; t < MT; ++t) Gt[t] = z4;
    #pragma unroll
    for (int ks = 0; ks < 4; ++ks) {
        short8 Bo = wfrag(OFF_OM1, ks, w, l);
        const int ko = ks * 32 + q8;
        #pragma unroll
        for (int t = 0; t < MT; ++t) {
            const int row = t * 16 + (l & 15);
            short8 Ai = *(const short8*)&sh_io[(row * IOSTR + ko) ^ lsz];
            Gt[t] = mfma16(Ai, Bo, Gt[t]);
        }
    }

    // ---- epilogue 2b (odd) + register reduction + store (no more barriers)
    float acc_o[4] = {0.f, 0.f, 0.f, 0.f};
    {
        const float bog = b_og[col];
        #pragma unroll
        for (int t = 0; t < MT; ++t)
            #pragma unroll
            for (int rg = 0; rg < 4; ++rg)
                acc_o[rg] += sgf(Go[t][rg] + bog) * thf(Gt[t][rg]);
    }
    #pragma unroll
    for (int rg = 0; rg < 4; ++rg) {               // sum the 4 lane-quads
        acc_e[rg] += __shfl_xor(acc_e[rg], 16);
        acc_e[rg] += __shfl_xor(acc_e[rg], 32);
        acc_o[rg] += __shfl_xor(acc_o[rg], 16);
        acc_o[rg] += __shfl_xor(acc_o[rg], 32);
    }
    {
        const int q = l >> 4;                      // this lane stores group q
        const float se = q == 0 ? acc_e[0] : q == 1 ? acc_e[1]
                       : q == 2 ? acc_e[2] : acc_e[3];
        const float so = q == 0 ? acc_o[0] : q == 1 ? acc_o[1]
                       : q == 2 ? acc_o[2] : acc_o[3];
        const long nb = (long)(n0 + q) * 64 + col;
        out[nb]                 = even_node[nb] + se;   // residual re-read (L2-hot)
        out[(long)NN * 64 + nb] = odd_node [nb] + so;
    }
}

extern "C" void kernel_launch(void* const* d_in, const int* in_sizes, int n_in,
                              void* d_out, int out_size, void* d_ws, size_t ws_size,
                              hipStream_t stream) {
    const float* even_node = (const float*)d_in[0];
    const float* odd_node  = (const float*)d_in[1];
    const float* nbr_fea   = (const float*)d_in[2];
    const int*   nbr_idx   = (const int*)d_in[3];
    const float* W_em1 = (const float*)d_in[4];
    const float* b_em1 = (const float*)d_in[5];
    const float* W_eg  = (const float*)d_in[6];
    const float* b_eg  = (const float*)d_in[7];
    const float* W_em2 = (const float*)d_in[8];
    const float* b_em2 = (const float*)d_in[9];
    const float* W_pej = (const float*)d_in[10];
    const float* b_pej = (const float*)d_in[11];
    const float* W_pei = (const float*)d_in[12];
    const float* b_pei = (const float*)d_in[13];
    const float* W_om1 = (const float*)d_in[14];
    const float* W_ogh = (const float*)d_in[15];
    const float* b_ogh = (const float*)d_in[16];
    const float* W_og  = (const float*)d_in[17];
    const float* b_og  = (const float*)d_in[18];

    static int s_attr_done = 0;                    // host-side config, idempotent
    if (!s_attr_done) {
        (void)hipFuncSetAttribute((const void*)eoconv_mfma,
                                  hipFuncAttributeMaxDynamicSharedMemorySize, LDS_SZ);
        s_attr_done = 1;
    }

    prepack<<<dim3(28), dim3(256), 0, stream>>>(W_em1, W_ogh, W_eg, W_em2,
                                                W_og, W_pej, W_pei, W_om1);
    eoconv_mfma<<<dim3(NN / GN), dim3(256), LDS_SZ, stream>>>(
        even_node, odd_node, nbr_fea, nbr_idx,
        b_em1, b_eg, b_em2, b_pej, b_pei, b_ogh, b_og,
        (float*)d_out);
}

// Round 7
// 444.397 us; speedup vs baseline: 2.1444x; 1.1623x over previous
//
#include <hip/hip_runtime.h>

// EvenOddConvLayer MFMA v8 (resubmit — R6 was an infra failure, kernel never ran).
// N=50000, M=20, EVEN=ODD=64, EDGE=32, CAT=224.
// v6/v7 (t-major GEMM2/3 + bf16 go_pk) fail the ODD output with error above
// the mathematical bound of that dataflow -> restructure abandoned.
// v8 = v5 EXACTLY (passed, 361us kernel) + ONE change: GEMM2 loop fission.
//   v5 held Gg/Gm/Go(60) + pk(20) + frags live at once (~127 regs) ->
//   scratch spill at the 128-reg budget of (256,4) (WRITE_SIZE 25->325MB).
//   v8: {Gg,Gm} -> acc_e (v5's epilogue 2a, same summation order) -> {Go}.
//   Peak live ~90 regs; dataflow/arithmetic byte-identical to v5.
// LDS 39680 (4 blk/CU), 5 barriers, __launch_bounds__(256,4).

#define NN    50000
#define GN    4
#define MT    5
#define ECSTR 128      // ej_cross row stride (shorts): [ej 0 | cross 64], swz
#define NSTR  40       // nbr row stride (shorts), no swz needed
#define ESTR  64       // eh / oh / oj row stride (shorts), swz
#define IOSTR 128      // io row stride (shorts): [ie 0 | ieo 64], swz

#define LDS_EJC 0      // ej_cross(20480) -> eh@0 oh@10240 -> io(20480)
#define LDS_NBR 20480  // nbr 80x40sh (6400)
#define LDS_OJ  26880  // oj 80x64sh (10240), swz
#define LDS_OIB 37120  // oi bf16 4x64 (512)
#define LDS_EIB 37632  // ei bf16 4x64 (512)
#define LDS_PG  38144  // per-group partials 3x4x64 bf16 (1536), bias folded
#define LDS_SZ  39680

typedef __attribute__((ext_vector_type(8))) short  short8;
typedef __attribute__((ext_vector_type(4))) float  floatx4;

__device__ unsigned char g_wbuf[114688];

#define OFF_EM1 0
#define OFF_OGH 28672
#define OFF_EG  57344
#define OFF_EM2 65536
#define OFF_OG  73728
#define OFF_PEJ 81920
#define OFF_PEI 90112
#define OFF_OM1 98304

__device__ __forceinline__ unsigned cvtpk(float lo, float hi) {   // 2x fp32->bf16 RNE
    unsigned r;
    asm("v_cvt_pk_bf16_f32 %0, %1, %2" : "=v"(r) : "v"(lo), "v"(hi));
    return r;
}
__device__ __forceinline__ unsigned short f2b(float x) {          // RNE fp32->bf16
    unsigned u = __float_as_uint(x);
    return (unsigned short)((u + 0x7fffu + ((u >> 16) & 1u)) >> 16);
}
__device__ __forceinline__ float b2f(unsigned short s) {
    return __uint_as_float(((unsigned)s) << 16);
}
__device__ __forceinline__ float spf(float x) {                   // softplus, fast
    return fmaxf(x, 0.f) + __logf(1.f + __expf(-fabsf(x)));
}
__device__ __forceinline__ float sgf(float x) {                   // sigmoid, fast
    return __builtin_amdgcn_rcpf(1.f + __expf(-x));
}
__device__ __forceinline__ float thf(float x) {                   // tanh, fast
    float e = __expf(-2.f * fabsf(x));
    float t = (1.f - e) * __builtin_amdgcn_rcpf(1.f + e);
    return __builtin_copysignf(t, x);
}
__device__ __forceinline__ floatx4 mfma16(short8 a, short8 b, floatx4 c) {
    return __builtin_amdgcn_mfma_f32_16x16x32_bf16(a, b, c, 0, 0, 0);
}
__device__ __forceinline__ short8 wfrag(int base, int s, int t, int l) {
    return *(const short8*)(g_wbuf + base + ((size_t)((s * 4 + t) * 64 + l)) * 16);
}

// ---------------- weight prepack (identical, verified) ----------------------
__global__ __launch_bounds__(256) void prepack(
    const float* __restrict__ W_em1, const float* __restrict__ W_ogh,
    const float* __restrict__ W_eg,  const float* __restrict__ W_em2,
    const float* __restrict__ W_og,  const float* __restrict__ W_pej,
    const float* __restrict__ W_pei, const float* __restrict__ W_om1)
{
    int tid = blockIdx.x * 256 + threadIdx.x;
    int gid = tid >> 6, l = tid & 63;
    const float* W; int base, gl;
    if      (gid < 28) { W = W_em1; base = OFF_EM1; gl = gid;      }
    else if (gid < 56) { W = W_ogh; base = OFF_OGH; gl = gid - 28; }
    else if (gid < 64) { W = W_eg;  base = OFF_EG;  gl = gid - 56; }
    else if (gid < 72) { W = W_em2; base = OFF_EM2; gl = gid - 64; }
    else if (gid < 80) { W = W_og;  base = OFF_OG;  gl = gid - 72; }
    else if (gid < 88) { W = W_pej; base = OFF_PEJ; gl = gid - 80; }
    else if (gid < 96) { W = W_pei; base = OFF_PEI; gl = gid - 88; }
    else               { W = W_om1; base = OFF_OM1; gl = gid - 96; }
    int s = gl >> 2, t = gl & 3;
    int k0 = s * 32 + (l >> 4) * 8;
    int n  = t * 16 + (l & 15);
    short8 pk;
    #pragma unroll
    for (int j = 0; j < 8; ++j) pk[j] = (short)f2b(W[(size_t)(k0 + j) * 64 + n]);
    *(short8*)(g_wbuf + base + ((size_t)((s * 4 + t) * 64 + l)) * 16) = pk;
}

// ---------------- main kernel ------------------------------------------------
__global__ __launch_bounds__(256, 4) void eoconv_mfma(
    const float* __restrict__ even_node, const float* __restrict__ odd_node,
    const float* __restrict__ nbr_fea,   const int* __restrict__ nbr_idx,
    const float* __restrict__ b_em1, const float* __restrict__ b_eg,
    const float* __restrict__ b_em2, const float* __restrict__ b_pej,
    const float* __restrict__ b_pei, const float* __restrict__ b_ogh,
    const float* __restrict__ b_og,  float* __restrict__ out)
{
    extern __shared__ char smem[];
    short* sh_ejc = (short*)(smem + LDS_EJC);
    short* sh_eh  = (short*)(smem + LDS_EJC);          // overlay after GEMM1
    short* sh_oh  = (short*)(smem + LDS_EJC + 10240);  // overlay after GEMM1
    short* sh_io  = (short*)(smem + LDS_EJC);          // overlay after GEMM2
    short* sh_nbr = (short*)(smem + LDS_NBR);
    short* sh_oj  = (short*)(smem + LDS_OJ);
    short* sh_oib = (short*)(smem + LDS_OIB);
    short* sh_eib = (short*)(smem + LDS_EIB);
    short* sh_pg  = (short*)(smem + LDS_PG);

    const int w  = threadIdx.x >> 6;
    const int l  = threadIdx.x & 63;
    const int n0 = blockIdx.x * GN;

    // ---- stage: wave w owns group w (rows 4*i+w). float4 gathers, 4 rows/iter.
    {
        const float eif = even_node[(long)(n0 + w) * 64 + l];
        const float oif = odd_node [(long)(n0 + w) * 64 + l];
        sh_oib[w * 64 + l] = (short)cvtpk(oif, oif);
        sh_eib[w * 64 + l] = (short)cvtpk(eif, eif);

        const long jb = (long)(n0 + w) * 20;
        int jv[5];
        #pragma unroll
        for (int c = 0; c < 5; ++c) jv[c] = nbr_idx[jb + c * 4 + (l >> 4)];

        const int c0 = (l & 15) * 4;               // this lane's 4 staging cols
        const float oi0 = __shfl(oif, c0), oi1 = __shfl(oif, c0 + 1);
        const float oi2 = __shfl(oif, c0 + 2), oi3 = __shfl(oif, c0 + 3);

        #pragma unroll
        for (int c = 0; c < 5; ++c) {
            const int  iw  = c * 4 + (l >> 4);     // pair index 0..19
            const int  row = iw * 4 + w;           // permuted row
            const int  j   = jv[c];
            const int  sz  = (row & 7) << 3;
            const float4 ej4 = *(const float4*)&even_node[(long)j * 64 + c0];
            const float4 oj4 = *(const float4*)&odd_node [(long)j * 64 + c0];
            *(int2*)&sh_ejc[(row * ECSTR + c0) ^ sz] =
                make_int2((int)cvtpk(ej4.x, ej4.y), (int)cvtpk(ej4.z, ej4.w));
            *(int2*)&sh_ejc[(row * ECSTR + 64 + c0) ^ sz] =
                make_int2((int)cvtpk(oi0 * oj4.x, oi1 * oj4.y),
                          (int)cvtpk(oi2 * oj4.z, oi3 * oj4.w));
            *(int2*)&sh_oj[(row * ESTR + c0) ^ sz] =
                make_int2((int)cvtpk(oj4.x, oj4.y), (int)cvtpk(oj4.z, oj4.w));
            const float2 nb2 = *(const float2*)&nbr_fea[(jb + iw) * 32 + (l & 15) * 2];
            *(int*)&sh_nbr[row * NSTR + (l & 15) * 2] = (int)cvtpk(nb2.x, nb2.y);
        }
    }
    __syncthreads();                               // s1: staging visible

    const int col = w * 16 + (l & 15);
    const int q8  = (l >> 4) * 8;
    const int q4  = (l >> 4) * 4;
    const int lsz = (l & 7) << 3;                  // swz for all A-read rows
    const floatx4 z4 = {0.f, 0.f, 0.f, 0.f};

    // ---- tiny GEMM: per-group ei @ {W_em1[0:64], W_ogh[0:64], W_pei} (rows 0..3)
    {
        const float be1 = b_em1[col], bgh = b_ogh[col], bpi = b_pei[col];
        floatx4 Tm = z4, Tg = z4, Tp = z4;
        #pragma unroll
        for (int ks = 0; ks < 2; ++ks) {
            short8 Ae = *(const short8*)&sh_eib[(l & 3) * 64 + ks * 32 + q8];
            Tm = mfma16(Ae, wfrag(OFF_EM1, ks, w, l), Tm);
            Tg = mfma16(Ae, wfrag(OFF_OGH, ks, w, l), Tg);
            Tp = mfma16(Ae, wfrag(OFF_PEI, ks, w, l), Tp);
        }
        if (l < 16) {                              // rows 0..3 = groups, bias folded
            #pragma unroll
            for (int rg = 0; rg < 4; ++rg) {
                sh_pg[      rg * 64 + col] = (short)cvtpk(Tm[rg] + be1, 0.f);
                sh_pg[256 + rg * 64 + col] = (short)cvtpk(Tg[rg] + bgh, 0.f);
                sh_pg[512 + rg * 64 + col] = (short)cvtpk(Tp[rg] + bpi, 0.f);
            }
        }
    }

    // ---- GEMM1: [ej|nbr|cross] @ {W_em1[64:],W_ogh[64:]}; ej @ W_pej
    floatx4 C1[MT], Cg[MT], Cpj[MT];
    #pragma unroll
    for (int t = 0; t < MT; ++t) { C1[t] = z4; Cg[t] = z4; Cpj[t] = z4; }
    #pragma unroll
    for (int ks = 0; ks < 5; ++ks) {
        short8 B1 = wfrag(OFF_EM1, ks + 2, w, l);
        short8 Bg = wfrag(OFF_OGH, ks + 2, w, l);
        short8 Bx = B1;
        if (ks < 2) Bx = wfrag(OFF_PEJ, ks, w, l);
        const int ko = ks * 32 + q8;
        #pragma unroll
        for (int t = 0; t < MT; ++t) {
            const int row = t * 16 + (l & 15);
            short8 A;
            if (ks == 2) A = *(const short8*)&sh_nbr[row * NSTR + q8];
            else         A = *(const short8*)&sh_ejc[(row * ECSTR +
                                (ks < 2 ? ko : ko - 32)) ^ lsz];
            C1[t] = mfma16(A, B1, C1[t]);
            Cg[t] = mfma16(A, Bg, Cg[t]);
            if (ks < 2) Cpj[t] = mfma16(A, Bx, Cpj[t]);
        }
    }
    __syncthreads();                               // s2: ej_cross dead -> eh/oh land

    // ---- epilogue 1 (v5-proven): eh/oh into old cat region; ie/ieo packed
    //      in pk regs; oj left intact.
    unsigned pk[MT][4];
    {
        const float bpj = b_pej[col];
        float em1g[4], oghg[4], peig[4], oiv[4];
        #pragma unroll
        for (int rg = 0; rg < 4; ++rg) {           // group == rg (row = 4i+g perm)
            em1g[rg] = b2f((unsigned short)sh_pg[      rg * 64 + col]);
            oghg[rg] = b2f((unsigned short)sh_pg[256 + rg * 64 + col]);
            peig[rg] = b2f((unsigned short)sh_pg[512 + rg * 64 + col]);
            oiv [rg] = b2f((unsigned short)sh_oib[rg * 64 + col]);
        }
        #pragma unroll
        for (int t = 0; t < MT; ++t) {
            #pragma unroll
            for (int rg = 0; rg < 4; ++rg) {
                const int row = t * 16 + q4 + rg;
                const int a   = (row * ESTR + col) ^ ((row & 7) << 3);
                const float ojr = b2f((unsigned short)sh_oj[a]);
                const float pj  = Cpj[t][rg] + bpj;
                pk[t][rg] = cvtpk(oiv[rg] * pj, peig[rg] * ojr);
                sh_eh[a] = (short)cvtpk(spf(C1[t][rg] + em1g[rg]), 0.f);
                sh_oh[a] = (short)cvtpk(spf(Cg[t][rg] + oghg[rg]), 0.f);
            }
        }
    }
    __syncthreads();                               // s3: eh/oh visible

    // ---- GEMM2a (fissioned, v5 dataflow): eh@{W_eg,W_em2} (K=64)
    float acc_e[4] = {0.f, 0.f, 0.f, 0.f};
    {
        floatx4 Gg[MT], Gm[MT];
        #pragma unroll
        for (int t = 0; t < MT; ++t) { Gg[t] = z4; Gm[t] = z4; }
        #pragma unroll
        for (int ks = 0; ks < 2; ++ks) {
            short8 Beg = wfrag(OFF_EG,  ks, w, l);
            short8 Bm2 = wfrag(OFF_EM2, ks, w, l);
            const int ko = ks * 32 + q8;
            #pragma unroll
            for (int t = 0; t < MT; ++t) {
                const int row = t * 16 + (l & 15);
                short8 Ae = *(const short8*)&sh_eh[(row * ESTR + ko) ^ lsz];
                Gg[t] = mfma16(Ae, Beg, Gg[t]);
                Gm[t] = mfma16(Ae, Bm2, Gm[t]);
            }
        }
        const float beg = b_eg[col], bm2 = b_em2[col];
        #pragma unroll
        for (int t = 0; t < MT; ++t)
            #pragma unroll
            for (int rg = 0; rg < 4; ++rg)
                acc_e[rg] += sgf(Gg[t][rg] + beg) * spf(Gm[t][rg] + bm2);
    }

    // ---- GEMM2b (fissioned, v5 dataflow): oh@W_og (K=64); Go stays f32
    floatx4 Go[MT];
    #pragma unroll
    for (int t = 0; t < MT; ++t) Go[t] = z4;
    #pragma unroll
    for (int ks = 0; ks < 2; ++ks) {
        short8 Bog = wfrag(OFF_OG, ks, w, l);
        const int ko = ks * 32 + q8;
        #pragma unroll
        for (int t = 0; t < MT; ++t) {
            const int row = t * 16 + (l & 15);
            short8 Ao = *(const short8*)&sh_oh[(row * ESTR + ko) ^ lsz];
            Go[t] = mfma16(Ao, Bog, Go[t]);
        }
    }
    __syncthreads();                               // s4: eh/oh dead -> io lands

    // ---- io store (v5-proven): [ie | ieo] into the dead eh|oh region
    #pragma unroll
    for (int t = 0; t < MT; ++t) {
        #pragma unroll
        for (int rg = 0; rg < 4; ++rg) {
            const int row = t * 16 + q4 + rg;
            const int sz  = (row & 7) << 3;
            sh_io[(row * IOSTR + col) ^ sz]      = (short)pk[t][rg];
            sh_io[(row * IOSTR + 64 + col) ^ sz] = (short)(pk[t][rg] >> 16);
        }
    }
    __syncthreads();                               // s5: io visible

    // ---- GEMM3 (v5-proven, ks-major): [ie|ieo] @ W_om1 (K=128)
    floatx4 Gt[MT];
    #pragma unroll
    for (int t = 0; t < MT; ++t) Gt[t] = z4;
    #pragma unroll
    for (int ks = 0; ks < 4; ++ks) {
        short8 Bo = wfrag(OFF_OM1, ks, w, l);
        const int ko = ks * 32 + q8;
        #pragma unroll
        for (int t = 0; t < MT; ++t) {
            const int row = t * 16 + (l & 15);
            short8 Ai = *(const short8*)&sh_io[(row * IOSTR + ko) ^ lsz];
            Gt[t] = mfma16(Ai, Bo, Gt[t]);
        }
    }

    // ---- epilogue 2b (v5-proven): odd gates * tanh, register accumulate
    float acc_o[4] = {0.f, 0.f, 0.f, 0.f};
    {
        const float bog = b_og[col];
        #pragma unroll
        for (int t = 0; t < MT; ++t)
            #pragma unroll
            for (int rg = 0; rg < 4; ++rg)
                acc_o[rg] += sgf(Go[t][rg] + bog) * thf(Gt[t][rg]);
    }

    // ---- register reduction across quarter-waves + residual + store
    #pragma unroll
    for (int rg = 0; rg < 4; ++rg) {
        acc_e[rg] += __shfl_xor(acc_e[rg], 16);
        acc_e[rg] += __shfl_xor(acc_e[rg], 32);
        acc_o[rg] += __shfl_xor(acc_o[rg], 16);
        acc_o[rg] += __shfl_xor(acc_o[rg], 32);
    }
    {
        const int q = l >> 4;                      // this lane stores group q
        const float se = q == 0 ? acc_e[0] : q == 1 ? acc_e[1]
                       : q == 2 ? acc_e[2] : acc_e[3];
        const float so = q == 0 ? acc_o[0] : q == 1 ? acc_o[1]
                       : q == 2 ? acc_o[2] : acc_o[3];
        const long nb = (long)(n0 + q) * 64 + col;
        out[nb]                 = even_node[nb] + se;   // residual re-read (L2-hot)
        out[(long)NN * 64 + nb] = odd_node [nb] + so;
    }
}

extern "C" void kernel_launch(void* const* d_in, const int* in_sizes, int n_in,
                              void* d_out, int out_size, void* d_ws, size_t ws_size,
                              hipStream_t stream) {
    const float* even_node = (const float*)d_in[0];
    const float* odd_node  = (const float*)d_in[1];
    const float* nbr_fea   = (const float*)d_in[2];
    const int*   nbr_idx   = (const int*)d_in[3];
    const float* W_em1 = (const float*)d_in[4];
    const float* b_em1 = (const float*)d_in[5];
    const float* W_eg  = (const float*)d_in[6];
    const float* b_eg  = (const float*)d_in[7];
    const float* W_em2 = (const float*)d_in[8];
    const float* b_em2 = (const float*)d_in[9];
    const float* W_pej = (const float*)d_in[10];
    const float* b_pej = (const float*)d_in[11];
    const float* W_pei = (const float*)d_in[12];
    const float* b_pei = (const float*)d_in[13];
    const float* W_om1 = (const float*)d_in[14];
    const float* W_ogh = (const float*)d_in[15];
    const float* b_ogh = (const float*)d_in[16];
    const float* W_og  = (const float*)d_in[17];
    const float* b_og  = (const float*)d_in[18];

    static int s_attr_done = 0;                    // host-side config, idempotent
    if (!s_attr_done) {
        (void)hipFuncSetAttribute((const void*)eoconv_mfma,
                                  hipFuncAttributeMaxDynamicSharedMemorySize, LDS_SZ);
        s_attr_done = 1;
    }

    prepack<<<dim3(28), dim3(256), 0, stream>>>(W_em1, W_ogh, W_eg, W_em2,
                                                W_og, W_pej, W_pei, W_om1);
    eoconv_mfma<<<dim3(NN / GN), dim3(256), LDS_SZ, stream>>>(
        even_node, odd_node, nbr_fea, nbr_idx,
        b_em1, b_eg, b_em2, b_pej, b_pei, b_ogh, b_og,
        (float*)d_out);
}

// Round 8
// 434.222 us; speedup vs baseline: 2.1946x; 1.0234x over previous
//
#include <hip/hip_runtime.h>

// EvenOddConvLayer MFMA v9. N=50000, M=20, EVEN=ODD=64, EDGE=32, CAT=224.
// v8 (291us, passed): VALUBusy 81% + Mfma 14% = issue-saturated; measured
// VALU-busy ~2.5x the algorithmic math -> suspected LDS addr recompute fat
// (XOR-swizzle defeats the compiler's affine offset folding).
// v9 = v8 dataflow byte-identical + hand-hoisted LDS addressing:
//   ((X + t*S) ^ swz) == (X ^ swz) + t*S holds exactly because swz touches
//   only bits 3-6 of the byte address and every loop step S (2048/4096 B)
//   is zero there (bit-disjointness checked per buffer). So each loop
//   computes ONE base pointer and indexes with compile-time byte offsets
//   that fold into ds-op offset immediates.
// LDS 39680 (4 blk/CU), 5 barriers, __launch_bounds__(256,4).

#define NN    50000
#define GN    4
#define MT    5
#define ECSTR 128      // ej_cross row stride (shorts): [ej 0 | cross 64], swz
#define NSTR  40       // nbr row stride (shorts), no swz needed
#define ESTR  64       // eh / oh / oj row stride (shorts), swz
#define IOSTR 128      // io row stride (shorts): [ie 0 | ieo 64], swz

#define LDS_EJC 0      // ej_cross(20480) -> eh@0 oh@10240 -> io(20480)
#define LDS_NBR 20480  // nbr 80x40sh (6400)
#define LDS_OJ  26880  // oj 80x64sh (10240), swz
#define LDS_OIB 37120  // oi bf16 4x64 (512)
#define LDS_EIB 37632  // ei bf16 4x64 (512)
#define LDS_PG  38144  // per-group partials 3x4x64 bf16 (1536), bias folded
#define LDS_SZ  39680

typedef __attribute__((ext_vector_type(8))) short  short8;
typedef __attribute__((ext_vector_type(4))) float  floatx4;

__device__ unsigned char g_wbuf[114688];

#define OFF_EM1 0
#define OFF_OGH 28672
#define OFF_EG  57344
#define OFF_EM2 65536
#define OFF_OG  73728
#define OFF_PEJ 81920
#define OFF_PEI 90112
#define OFF_OM1 98304

__device__ __forceinline__ unsigned cvtpk(float lo, float hi) {   // 2x fp32->bf16 RNE
    unsigned r;
    asm("v_cvt_pk_bf16_f32 %0, %1, %2" : "=v"(r) : "v"(lo), "v"(hi));
    return r;
}
__device__ __forceinline__ unsigned short f2b(float x) {          // RNE fp32->bf16
    unsigned u = __float_as_uint(x);
    return (unsigned short)((u + 0x7fffu + ((u >> 16) & 1u)) >> 16);
}
__device__ __forceinline__ float b2f(unsigned short s) {
    return __uint_as_float(((unsigned)s) << 16);
}
__device__ __forceinline__ float spf(float x) {                   // softplus, fast
    return fmaxf(x, 0.f) + __logf(1.f + __expf(-fabsf(x)));
}
__device__ __forceinline__ float sgf(float x) {                   // sigmoid, fast
    return __builtin_amdgcn_rcpf(1.f + __expf(-x));
}
__device__ __forceinline__ float thf(float x) {                   // tanh, fast
    float e = __expf(-2.f * fabsf(x));
    float t = (1.f - e) * __builtin_amdgcn_rcpf(1.f + e);
    return __builtin_copysignf(t, x);
}
__device__ __forceinline__ floatx4 mfma16(short8 a, short8 b, floatx4 c) {
    return __builtin_amdgcn_mfma_f32_16x16x32_bf16(a, b, c, 0, 0, 0);
}
__device__ __forceinline__ short8 wfrag(int base, int s, int t, int l) {
    return *(const short8*)(g_wbuf + base + ((size_t)((s * 4 + t) * 64 + l)) * 16);
}
__device__ __forceinline__ short8 lds8(const void* base, int byteoff) {
    return *(const short8*)((const char*)base + byteoff);
}

// ---------------- weight prepack (identical, verified) ----------------------
__global__ __launch_bounds__(256) void prepack(
    const float* __restrict__ W_em1, const float* __restrict__ W_ogh,
    const float* __restrict__ W_eg,  const float* __restrict__ W_em2,
    const float* __restrict__ W_og,  const float* __restrict__ W_pej,
    const float* __restrict__ W_pei, const float* __restrict__ W_om1)
{
    int tid = blockIdx.x * 256 + threadIdx.x;
    int gid = tid >> 6, l = tid & 63;
    const float* W; int base, gl;
    if      (gid < 28) { W = W_em1; base = OFF_EM1; gl = gid;      }
    else if (gid < 56) { W = W_ogh; base = OFF_OGH; gl = gid - 28; }
    else if (gid < 64) { W = W_eg;  base = OFF_EG;  gl = gid - 56; }
    else if (gid < 72) { W = W_em2; base = OFF_EM2; gl = gid - 64; }
    else if (gid < 80) { W = W_og;  base = OFF_OG;  gl = gid - 72; }
    else if (gid < 88) { W = W_pej; base = OFF_PEJ; gl = gid - 80; }
    else if (gid < 96) { W = W_pei; base = OFF_PEI; gl = gid - 88; }
    else               { W = W_om1; base = OFF_OM1; gl = gid - 96; }
    int s = gl >> 2, t = gl & 3;
    int k0 = s * 32 + (l >> 4) * 8;
    int n  = t * 16 + (l & 15);
    short8 pk;
    #pragma unroll
    for (int j = 0; j < 8; ++j) pk[j] = (short)f2b(W[(size_t)(k0 + j) * 64 + n]);
    *(short8*)(g_wbuf + base + ((size_t)((s * 4 + t) * 64 + l)) * 16) = pk;
}

// ---------------- main kernel ------------------------------------------------
__global__ __launch_bounds__(256, 4) void eoconv_mfma(
    const float* __restrict__ even_node, const float* __restrict__ odd_node,
    const float* __restrict__ nbr_fea,   const int* __restrict__ nbr_idx,
    const float* __restrict__ b_em1, const float* __restrict__ b_eg,
    const float* __restrict__ b_em2, const float* __restrict__ b_pej,
    const float* __restrict__ b_pei, const float* __restrict__ b_ogh,
    const float* __restrict__ b_og,  float* __restrict__ out)
{
    extern __shared__ char smem[];
    short* sh_ejc = (short*)(smem + LDS_EJC);
    short* sh_eh  = (short*)(smem + LDS_EJC);          // overlay after GEMM1
    short* sh_oh  = (short*)(smem + LDS_EJC + 10240);  // overlay after GEMM1
    short* sh_io  = (short*)(smem + LDS_EJC);          // overlay after GEMM2
    short* sh_nbr = (short*)(smem + LDS_NBR);
    short* sh_oj  = (short*)(smem + LDS_OJ);
    short* sh_oib = (short*)(smem + LDS_OIB);
    short* sh_eib = (short*)(smem + LDS_EIB);
    short* sh_pg  = (short*)(smem + LDS_PG);

    const int w  = threadIdx.x >> 6;
    const int l  = threadIdx.x & 63;
    const int n0 = blockIdx.x * GN;

    // ---- stage: wave w owns group w (rows 4*i+w). float4 gathers, 4 rows/iter.
    {
        const float eif = even_node[(long)(n0 + w) * 64 + l];
        const float oif = odd_node [(long)(n0 + w) * 64 + l];
        sh_oib[w * 64 + l] = (short)cvtpk(oif, oif);
        sh_eib[w * 64 + l] = (short)cvtpk(eif, eif);

        const long jb = (long)(n0 + w) * 20;
        int jv[5];
        #pragma unroll
        for (int c = 0; c < 5; ++c) jv[c] = nbr_idx[jb + c * 4 + (l >> 4)];

        const int c0 = (l & 15) * 4;               // this lane's 4 staging cols
        const float oi0 = __shfl(oif, c0), oi1 = __shfl(oif, c0 + 1);
        const float oi2 = __shfl(oif, c0 + 2), oi3 = __shfl(oif, c0 + 3);

        // hoisted bases: row = 16c + r0s, r0s = (l>>4)*4 + w; (row&7) c-invariant
        const int r0s = (l >> 4) * 4 + w;
        const int szs = (r0s & 7) << 3;
        char* ej_b = (char*)sh_ejc + (((r0s * ECSTR + c0) ^ szs) * 2);        // +c*4096
        char* cr_b = (char*)sh_ejc + (((r0s * ECSTR + 64 + c0) ^ szs) * 2);   // +c*4096
        char* oj_b = (char*)sh_oj  + (((r0s * ESTR + c0) ^ szs) * 2);         // +c*2048
        char* nb_b = (char*)sh_nbr + (r0s * NSTR + (l & 15) * 2) * 2;         // +c*1280

        #pragma unroll
        for (int c = 0; c < 5; ++c) {
            const int  iw = c * 4 + (l >> 4);      // pair index 0..19
            const int  j  = jv[c];
            const float4 ej4 = *(const float4*)&even_node[(long)j * 64 + c0];
            const float4 oj4 = *(const float4*)&odd_node [(long)j * 64 + c0];
            *(int2*)(ej_b + c * 4096) =
                make_int2((int)cvtpk(ej4.x, ej4.y), (int)cvtpk(ej4.z, ej4.w));
            *(int2*)(cr_b + c * 4096) =
                make_int2((int)cvtpk(oi0 * oj4.x, oi1 * oj4.y),
                          (int)cvtpk(oi2 * oj4.z, oi3 * oj4.w));
            *(int2*)(oj_b + c * 2048) =
                make_int2((int)cvtpk(oj4.x, oj4.y), (int)cvtpk(oj4.z, oj4.w));
            const float2 nb2 = *(const float2*)&nbr_fea[(jb + iw) * 32 + (l & 15) * 2];
            *(int*)(nb_b + c * 1280) = (int)cvtpk(nb2.x, nb2.y);
        }
    }
    __syncthreads();                               // s1: staging visible

    const int col = w * 16 + (l & 15);
    const int q8  = (l >> 4) * 8;
    const int q4  = (l >> 4) * 4;
    const int lsz = (l & 7) << 3;                  // swz for all A-read rows
    const floatx4 z4 = {0.f, 0.f, 0.f, 0.f};

    // ---- tiny GEMM: per-group ei @ {W_em1[0:64], W_ogh[0:64], W_pei} (rows 0..3)
    {
        const float be1 = b_em1[col], bgh = b_ogh[col], bpi = b_pei[col];
        floatx4 Tm = z4, Tg = z4, Tp = z4;
        #pragma unroll
        for (int ks = 0; ks < 2; ++ks) {
            short8 Ae = *(const short8*)&sh_eib[(l & 3) * 64 + ks * 32 + q8];
            Tm = mfma16(Ae, wfrag(OFF_EM1, ks, w, l), Tm);
            Tg = mfma16(Ae, wfrag(OFF_OGH, ks, w, l), Tg);
            Tp = mfma16(Ae, wfrag(OFF_PEI, ks, w, l), Tp);
        }
        if (l < 16) {                              // rows 0..3 = groups, bias folded
            #pragma unroll
            for (int rg = 0; rg < 4; ++rg) {
                sh_pg[      rg * 64 + col] = (short)cvtpk(Tm[rg] + be1, 0.f);
                sh_pg[256 + rg * 64 + col] = (short)cvtpk(Tg[rg] + bgh, 0.f);
                sh_pg[512 + rg * 64 + col] = (short)cvtpk(Tp[rg] + bpi, 0.f);
            }
        }
    }

    // ---- GEMM1: [ej|nbr|cross] @ {W_em1[64:],W_ogh[64:]}; ej @ W_pej
    floatx4 C1[MT], Cg[MT], Cpj[MT];
    #pragma unroll
    for (int t = 0; t < MT; ++t) { C1[t] = z4; Cg[t] = z4; Cpj[t] = z4; }
    #pragma unroll
    for (int ks = 0; ks < 5; ++ks) {
        short8 B1 = wfrag(OFF_EM1, ks + 2, w, l);
        short8 Bg = wfrag(OFF_OGH, ks + 2, w, l);
        short8 Bx = B1;
        if (ks < 2) Bx = wfrag(OFF_PEJ, ks, w, l);
        const int ko = ks * 32 + q8;
        // hoisted base: row = t*16 + (l&15); (row&7) = l&7 t-invariant
        const char* ab; int step;
        if (ks == 2) { ab = (const char*)sh_nbr + ((l & 15) * NSTR + q8) * 2;
                       step = 16 * NSTR * 2; }
        else {
            const int off = (ks < 2) ? ko : (ko - 32);
            ab = (const char*)sh_ejc + ((((l & 15) * ECSTR + off) ^ lsz) * 2);
            step = 16 * ECSTR * 2;
        }
        #pragma unroll
        for (int t = 0; t < MT; ++t) {
            short8 A = lds8(ab, t * step);
            C1[t] = mfma16(A, B1, C1[t]);
            Cg[t] = mfma16(A, Bg, Cg[t]);
            if (ks < 2) Cpj[t] = mfma16(A, Bx, Cpj[t]);
        }
    }
    __syncthreads();                               // s2: ej_cross dead -> eh/oh land

    // ---- epilogue 1 (v8 dataflow): eh/oh into old cat region; ie/ieo packed
    //      in pk regs; oj left intact. Hoisted per-rg bases, step t*2048 B.
    unsigned pk[MT][4];
    {
        const float bpj = b_pej[col];
        float em1g[4], oghg[4], peig[4], oiv[4];
        int eb[4];                                 // byte offset within eh/oh/oj
        #pragma unroll
        for (int rg = 0; rg < 4; ++rg) {           // group == rg (row = 4i+g perm)
            em1g[rg] = b2f((unsigned short)sh_pg[      rg * 64 + col]);
            oghg[rg] = b2f((unsigned short)sh_pg[256 + rg * 64 + col]);
            peig[rg] = b2f((unsigned short)sh_pg[512 + rg * 64 + col]);
            oiv [rg] = b2f((unsigned short)sh_oib[rg * 64 + col]);
            const int r0 = q4 + rg;                // (row&7) = r0&7, t-invariant
            eb[rg] = (((r0 * ESTR + col) ^ ((r0 & 7) << 3)) * 2);
        }
        #pragma unroll
        for (int t = 0; t < MT; ++t) {
            #pragma unroll
            for (int rg = 0; rg < 4; ++rg) {
                const int a = eb[rg] + t * 2048;
                const float ojr = b2f(*(const unsigned short*)((char*)sh_oj + a));
                const float pj  = Cpj[t][rg] + bpj;
                pk[t][rg] = cvtpk(oiv[rg] * pj, peig[rg] * ojr);
                *(short*)((char*)sh_eh + a) =
                    (short)cvtpk(spf(C1[t][rg] + em1g[rg]), 0.f);
                *(short*)((char*)sh_oh + a) =
                    (short)cvtpk(spf(Cg[t][rg] + oghg[rg]), 0.f);
            }
        }
    }
    __syncthreads();                               // s3: eh/oh visible

    // ---- GEMM2a (fissioned): eh@{W_eg,W_em2} (K=64); hoisted bases
    float acc_e[4] = {0.f, 0.f, 0.f, 0.f};
    {
        floatx4 Gg[MT], Gm[MT];
        #pragma unroll
        for (int t = 0; t < MT; ++t) { Gg[t] = z4; Gm[t] = z4; }
        #pragma unroll
        for (int ks = 0; ks < 2; ++ks) {
            short8 Beg = wfrag(OFF_EG,  ks, w, l);
            short8 Bm2 = wfrag(OFF_EM2, ks, w, l);
            const int boff = ((((l & 15) * ESTR + ks * 32 + q8) ^ lsz) * 2);
            const char* ae = (const char*)sh_eh + boff;
            #pragma unroll
            for (int t = 0; t < MT; ++t) {
                short8 Ae = lds8(ae, t * 2048);
                Gg[t] = mfma16(Ae, Beg, Gg[t]);
                Gm[t] = mfma16(Ae, Bm2, Gm[t]);
            }
        }
        const float beg = b_eg[col], bm2 = b_em2[col];
        #pragma unroll
        for (int t = 0; t < MT; ++t)
            #pragma unroll
            for (int rg = 0; rg < 4; ++rg)
                acc_e[rg] += sgf(Gg[t][rg] + beg) * spf(Gm[t][rg] + bm2);
    }

    // ---- GEMM2b (fissioned): oh@W_og (K=64); Go stays f32
    floatx4 Go[MT];
    #pragma unroll
    for (int t = 0; t < MT; ++t) Go[t] = z4;
    #pragma unroll
    for (int ks = 0; ks < 2; ++ks) {
        short8 Bog = wfrag(OFF_OG, ks, w, l);
        const int boff = ((((l & 15) * ESTR + ks * 32 + q8) ^ lsz) * 2);
        const char* ao = (const char*)sh_oh + boff;
        #pragma unroll
        for (int t = 0; t < MT; ++t) {
            short8 Ao = lds8(ao, t * 2048);
            Go[t] = mfma16(Ao, Bog, Go[t]);
        }
    }
    __syncthreads();                               // s4: eh/oh dead -> io lands

    // ---- io store: [ie | ieo] into the dead eh|oh region; hoisted bases
    {
        int iob[4];
        #pragma unroll
        for (int rg = 0; rg < 4; ++rg) {
            const int r0 = q4 + rg;
            iob[rg] = (((r0 * IOSTR + col) ^ ((r0 & 7) << 3)) * 2);
        }
        #pragma unroll
        for (int t = 0; t < MT; ++t) {
            #pragma unroll
            for (int rg = 0; rg < 4; ++rg) {
                const int a = iob[rg] + t * 4096;
                *(short*)((char*)sh_io + a)       = (short)pk[t][rg];
                *(short*)((char*)sh_io + a + 128) = (short)(pk[t][rg] >> 16);
            }
        }
    }
    __syncthreads();                               // s5: io visible

    // ---- GEMM3 (ks-major): [ie|ieo] @ W_om1 (K=128); hoisted bases
    floatx4 Gt[MT];
    #pragma unroll
    for (int t = 0; t < MT; ++t) Gt[t] = z4;
    #pragma unroll
    for (int ks = 0; ks < 4; ++ks) {
        short8 Bo = wfrag(OFF_OM1, ks, w, l);
        const int boff = ((((l & 15) * IOSTR + ks * 32 + q8) ^ lsz) * 2);
        const char* ai = (const char*)sh_io + boff;
        #pragma unroll
        for (int t = 0; t < MT; ++t) {
            short8 Ai = lds8(ai, t * 4096);
            Gt[t] = mfma16(Ai, Bo, Gt[t]);
        }
    }

    // ---- epilogue 2b: odd gates * tanh, register accumulate
    float acc_o[4] = {0.f, 0.f, 0.f, 0.f};
    {
        const float bog = b_og[col];
        #pragma unroll
        for (int t = 0; t < MT; ++t)
            #pragma unroll
            for (int rg = 0; rg < 4; ++rg)
                acc_o[rg] += sgf(Go[t][rg] + bog) * thf(Gt[t][rg]);
    }

    // ---- register reduction across quarter-waves + residual + store
    #pragma unroll
    for (int rg = 0; rg < 4; ++rg) {
        acc_e[rg] += __shfl_xor(acc_e[rg], 16);
        acc_e[rg] += __shfl_xor(acc_e[rg], 32);
        acc_o[rg] += __shfl_xor(acc_o[rg], 16);
        acc_o[rg] += __shfl_xor(acc_o[rg], 32);
    }
    {
        const int q = l >> 4;                      // this lane stores group q
        const float se = q == 0 ? acc_e[0] : q == 1 ? acc_e[1]
                       : q == 2 ? acc_e[2] : acc_e[3];
        const float so = q == 0 ? acc_o[0] : q == 1 ? acc_o[1]
                       : q == 2 ? acc_o[2] : acc_o[3];
        const long nb = (long)(n0 + q) * 64 + col;
        out[nb]                 = even_node[nb] + se;   // residual re-read (L2-hot)
        out[(long)NN * 64 + nb] = odd_node [nb] + so;
    }
}

extern "C" void kernel_launch(void* const* d_in, const int* in_sizes, int n_in,
                              void* d_out, int out_size, void* d_ws, size_t ws_size,
                              hipStream_t stream) {
    const float* even_node = (const float*)d_in[0];
    const float* odd_node  = (const float*)d_in[1];
    const float* nbr_fea   = (const float*)d_in[2];
    const int*   nbr_idx   = (const int*)d_in[3];
    const float* W_em1 = (const float*)d_in[4];
    const float* b_em1 = (const float*)d_in[5];
    const float* W_eg  = (const float*)d_in[6];
    const float* b_eg  = (const float*)d_in[7];
    const float* W_em2 = (const float*)d_in[8];
    const float* b_em2 = (const float*)d_in[9];
    const float* W_pej = (const float*)d_in[10];
    const float* b_pej = (const float*)d_in[11];
    const float* W_pei = (const float*)d_in[12];
    const float* b_pei = (const float*)d_in[13];
    const float* W_om1 = (const float*)d_in[14];
    const float* W_ogh = (const float*)d_in[15];
    const float* b_ogh = (const float*)d_in[16];
    const float* W_og  = (const float*)d_in[17];
    const float* b_og  = (const float*)d_in[18];

    static int s_attr_done = 0;                    // host-side config, idempotent
    if (!s_attr_done) {
        (void)hipFuncSetAttribute((const void*)eoconv_mfma,
                                  hipFuncAttributeMaxDynamicSharedMemorySize, LDS_SZ);
        s_attr_done = 1;
    }

    prepack<<<dim3(28), dim3(256), 0, stream>>>(W_em1, W_ogh, W_eg, W_em2,
                                                W_og, W_pej, W_pei, W_om1);
    eoconv_mfma<<<dim3(NN / GN), dim3(256), LDS_SZ, stream>>>(
        even_node, odd_node, nbr_fea, nbr_idx,
        b_em1, b_eg, b_em2, b_pej, b_pei, b_ogh, b_og,
        (float*)d_out);
}